// Round 15
// baseline (240.092 us; speedup 1.0000x reference)
//
#include <hip/hip_runtime.h>

#define NB 16
#define NC 512
#define NSP 1024
#define OQKV 1536
#define EPSV 1e-5f

typedef unsigned short u16;
typedef unsigned int u32;
typedef __attribute__((ext_vector_type(8))) short short8;
typedef __attribute__((ext_vector_type(4))) float f32x4;
typedef __attribute__((ext_vector_type(16))) float f32x16;

__device__ __forceinline__ float us2f(u16 u) {
  return __uint_as_float(((u32)u) << 16);
}
__device__ __forceinline__ u16 f2us(float f) {  // RNE f32->bf16
  u32 x = __float_as_uint(f);
  return (u16)((x + 0x7fffu + ((x >> 16) & 1u)) >> 16);
}
#if __has_builtin(__builtin_amdgcn_cvt_pk_bf16_f32)
typedef __attribute__((ext_vector_type(2))) __bf16 bf16x2_t;
__device__ __forceinline__ u32 pack2(float a, float b) {
  bf16x2_t r = __builtin_amdgcn_cvt_pk_bf16_f32(a, b);
  return *reinterpret_cast<u32*>(&r);
}
#else
__device__ __forceinline__ u32 pack2(float a, float b) {
  return (u32)f2us(a) | ((u32)f2us(b) << 16);
}
#endif
__device__ __forceinline__ float ld1(const void* p, size_t i, bool f32) {
  return f32 ? ((const float*)p)[i] : us2f(((const u16*)p)[i]);
}
// wave-uniform input-dtype detection (fp32 low-halves are random mantissa)
__device__ __forceinline__ bool detect_f32(const void* x0) {
  const u32* xw = (const u32*)x0;
  u32 w = xw[threadIdx.x & 63];
  u32 e = ((w & 0xffffu) >> 7) & 0xffu;
  bool sane = (e >= 0x60u && e <= 0x9fu);
  return __popcll(__ballot(sane)) < 32;
}

// async global->LDS, 16B per lane; lds ptr must be wave-uniform
typedef const __attribute__((address_space(1))) unsigned int* gas_t;
typedef __attribute__((address_space(3))) unsigned int* las_t;
__device__ __forceinline__ void gload16(const void* g, void* l) {
  __builtin_amdgcn_global_load_lds((gas_t)g, (las_t)l, 16, 0, 0);
}

// ---- GroupNorm partial sums: one block per (b,g,half); 32768 elems ----
__global__ __launch_bounds__(256) void gn_partial(
    const void* __restrict__ x, float2* __restrict__ part) {
  bool f32 = detect_f32(x);
  int idx = blockIdx.x;
  size_t base = (size_t)idx * 32768;
  float s1 = 0.f, s2 = 0.f;
  for (int i = threadIdx.x; i < 4096; i += 256) {
    float f[8];
    if (f32) {
      float4 a = *((const float4*)x + (base >> 2) + i * 2);
      float4 b = *((const float4*)x + (base >> 2) + i * 2 + 1);
      f[0]=a.x; f[1]=a.y; f[2]=a.z; f[3]=a.w; f[4]=b.x; f[5]=b.y; f[6]=b.z; f[7]=b.w;
    } else {
      uint4 p = *((const uint4*)x + (base >> 3) + i);
      f[0]=us2f((u16)(p.x&0xffffu)); f[1]=us2f((u16)(p.x>>16));
      f[2]=us2f((u16)(p.y&0xffffu)); f[3]=us2f((u16)(p.y>>16));
      f[4]=us2f((u16)(p.z&0xffffu)); f[5]=us2f((u16)(p.z>>16));
      f[6]=us2f((u16)(p.w&0xffffu)); f[7]=us2f((u16)(p.w>>16));
    }
#pragma unroll
    for (int m = 0; m < 8; m++) { s1 += f[m]; s2 += f[m] * f[m]; }
  }
  __shared__ float r1[256], r2[256];
  r1[threadIdx.x] = s1; r2[threadIdx.x] = s2;
  __syncthreads();
  for (int s = 128; s > 0; s >>= 1) {
    if ((int)threadIdx.x < s) {
      r1[threadIdx.x] += r1[threadIdx.x + s];
      r2[threadIdx.x] += r2[threadIdx.x + s];
    }
    __syncthreads();
  }
  if (threadIdx.x == 0) part[idx] = make_float2(r1[0], r2[0]);
}

// ---- fused prep: weight converts + GN-apply/transpose (stats inline) ----
__global__ __launch_bounds__(256) void prep_all(
    const void* __restrict__ x, const float2* __restrict__ part,
    const void* __restrict__ gamma, const void* __restrict__ beta,
    const void* __restrict__ qkvw, const void* __restrict__ projw,
    u16* __restrict__ wq, u16* __restrict__ wp, u16* __restrict__ xnt) {
  bool f32 = detect_f32(x);
  int p = blockIdx.x;
  int t = threadIdx.x;
  if (p < 512) {  // ---- weight fp32->bf16 convert (or copy) ----
    const void* src = (p < 384) ? qkvw : projw;
    u16* dst = (p < 384) ? wq : wp;
    size_t e = ((size_t)(p < 384 ? p : p - 384) * 256 + t) * 8;
    uint4 v;
    if (f32) {
      float4 a = *(const float4*)((const float*)src + e);
      float4 b = *(const float4*)((const float*)src + e + 4);
      v.x = pack2(a.x, a.y); v.y = pack2(a.z, a.w);
      v.z = pack2(b.x, b.y); v.w = pack2(b.z, b.w);
    } else {
      v = *(const uint4*)((const u16*)src + e);
    }
    *(uint4*)(dst + e) = v;
    return;
  }
  int q = p - 512;
  int b = q >> 7;
  int c0 = ((q >> 4) & 7) << 6;
  int n0 = (q & 15) << 6;
  __shared__ __align__(16) u16 T[64 * 64];
  int cc = t >> 4;         // 0..15
  int nn = (t & 15) << 2;  // 0..60
  float2 pa = part[((b << 3) + (c0 >> 6)) * 2];
  float2 pb = part[((b << 3) + (c0 >> 6)) * 2 + 1];
  float mean = (pa.x + pb.x) * (1.f / 65536.f);
  float var = (pa.y + pb.y) * (1.f / 65536.f) - mean * mean;
  float inv = rsqrtf(var + EPSV);
#pragma unroll
  for (int rep = 0; rep < 4; rep++) {
    int cl = cc + (rep << 4);     // c-local 0..63
    int c = c0 + cl;
    float g = ld1(gamma, c, f32), be = ld1(beta, c, f32);
    float wsc = g * inv, bsc = be - mean * wsc;
    size_t xb = ((size_t)b * NC + c) * NSP + n0 + nn;
    float f[4];
    if (f32) {
      float4 v = *(const float4*)((const float*)x + xb);
      f[0]=v.x; f[1]=v.y; f[2]=v.z; f[3]=v.w;
    } else {
      uint2 v = *(const uint2*)((const u16*)x + xb);
      f[0]=us2f((u16)(v.x&0xffffu)); f[1]=us2f((u16)(v.x>>16));
      f[2]=us2f((u16)(v.y&0xffffu)); f[3]=us2f((u16)(v.y>>16));
    }
#pragma unroll
    for (int j = 0; j < 4; j++) {
      int n = nn + j;
      T[(n << 6) + (((cl & ~7) ^ ((n & 7) << 3)) | (cl & 7))] =
          f2us(fmaf(f[j], wsc, bsc));
    }
  }
  __syncthreads();
#pragma unroll
  for (int i = 0; i < 2; i++) {
    int slot = (i << 8) + t;
    int nl = slot >> 3;         // 0..63
    int cs = (slot & 7) << 3;   // 0..56
    uint4 v = *(const uint4*)&T[(nl << 6) + (cs ^ ((nl & 7) << 3))];
    *(uint4*)&xnt[((size_t)b * NSP + n0 + nl) * NC + c0 + cs] = v;
  }
}

// ---- MFMA GEMM: out[b,o,n] = W[o,:].XnT[b,n,:] + bias. BK=64: 8 K-chunks
// x 2 barriers. LDS 32KB. Staging slot s=i*256+t: row=i*32+(t>>3), src seg
// = (t&7)^((t>>3)&7); reads XOR the same way (rule 21). Batch-grouping XCD
// swizzle (T1): xcd p&7 owns batches {2*xcd, 2*xcd+1}.
template <bool OUTRAW, bool RES>
__global__ __launch_bounds__(256) void mfma_gemm(
    const u16* __restrict__ W, const u16* __restrict__ Xt,
    const void* __restrict__ xdet, const void* __restrict__ bias,
    const void* __restrict__ res, void* __restrict__ out, int O) {
  bool f32 = detect_f32(xdet);
  bool of = OUTRAW && f32;
  int gy = O >> 7;                     // grid y-dim (12 or 4)
  int bpb = gy << 3;                   // blocks per batch
  int p = blockIdx.x + (blockIdx.y << 3) + blockIdx.z * bpb;
  int k = p >> 3;
  int b = ((p & 7) << 1) + (k >= bpb ? 1 : 0);
  int r = k - (k >= bpb ? bpb : 0);
  int orow = (r >> 3) << 7;
  int ncol = (r & 7) << 7;
  int t = threadIdx.x;
  int lane = t & 63, w = t >> 6;
  int wo = (w >> 1) << 6, wn = (w & 1) << 6;
  int l15 = lane & 15, quad = lane >> 4;

  __shared__ __align__(16) u16 Alds[128 * 64];
  __shared__ __align__(16) u16 Blds[128 * 64];

  f32x4 acc[4][4];
#pragma unroll
  for (int i = 0; i < 4; i++)
#pragma unroll
    for (int j = 0; j < 4; j++) acc[i][j] = (f32x4){0.f, 0.f, 0.f, 0.f};

  int srow = t >> 3;                        // staging base row (call i adds i*32)
  int seg = (t & 7) ^ (srow & 7);           // source 16B-segment (call-invariant)
  const u16* wpA = W + (size_t)(orow + srow) * NC + (seg << 3);
  const u16* xpB = Xt + ((size_t)b * NSP + ncol + srow) * NC + (seg << 3);

  for (int k0 = 0; k0 < NC; k0 += 64) {
    __syncthreads();  // prior chunk's frag reads done
#pragma unroll
    for (int i = 0; i < 4; i++) {
      gload16(wpA + k0 + (size_t)i * (32 * NC), &Alds[(i << 11) + (w << 9)]);
      gload16(xpB + k0 + (size_t)i * (32 * NC), &Blds[(i << 11) + (w << 9)]);
    }
    __syncthreads();  // compiler drains vmcnt(0) before barrier
#pragma unroll
    for (int kk = 0; kk < 2; kk++) {
      short8 af[4], bf[4];
#pragma unroll
      for (int ot = 0; ot < 4; ot++) {
        int rr = wo + ot * 16 + l15;
        af[ot] = *(const short8*)&Alds[(rr << 6) + ((((kk << 2) + quad) ^ (rr & 7)) << 3)];
      }
#pragma unroll
      for (int nt = 0; nt < 4; nt++) {
        int rr = wn + nt * 16 + l15;
        bf[nt] = *(const short8*)&Blds[(rr << 6) + ((((kk << 2) + quad) ^ (rr & 7)) << 3)];
      }
#pragma unroll
      for (int ot = 0; ot < 4; ot++)
#pragma unroll
        for (int nt = 0; nt < 4; nt++)
          acc[ot][nt] = __builtin_amdgcn_mfma_f32_16x16x32_bf16(
              af[ot], bf[nt], acc[ot][nt], 0, 0, 0);
    }
  }
  // ---- epilogue ----
#pragma unroll
  for (int ot = 0; ot < 4; ot++) {
#pragma unroll
    for (int rr = 0; rr < 4; rr++) {
      int o = orow + wo + ot * 16 + (quad << 2) + rr;
      float bs = ld1(bias, o, f32);
      size_t rowb = ((size_t)b * O + o) * NSP + ncol + wn + l15;
#pragma unroll
      for (int nt = 0; nt < 4; nt++) {
        size_t idx = rowb + nt * 16;
        float v = acc[ot][nt][rr] + bs;
        if (RES) v += ld1(res, idx, f32);
        if (of) ((float*)out)[idx] = v;
        else ((u16*)out)[idx] = f2us(v);
      }
    }
  }
}

// ---- MFMA attention: 512-thread block = 256 q of one (b,h); 8 waves. ----
// r14 structure (32x32x16 MFMA, P in registers, permlane32 exchange, twin
// K/V buffers 1 barrier/chunk, XCD swizzle). This round: softmax VALU cut.
// (1) Q pre-scaled by log2e/64 -> P = exp2f(S) (bare v_exp_f32; deletes
//     the x*log2e mul inside __expf). Logit sigma ~0.125, so the bf16
//     rounding of the new scale perturbs logits by ~5e-4 — harmless.
// (2) lsum via ones-MFMA: mfma(ones, pf, lsacc) accumulates column sums of
//     the SAME bf16 P fed to PV; all 16 regs identical -> invL=1/lsacc[0],
//     no lsum adds, no final shfl. +4 MFMA/chunk on a 23%-utilized pipe.
// Reg: +16 (lsacc) -> ~80-96, still >=4 waves/SIMD; spill sentinel = WRITE.
__global__ __launch_bounds__(512, 4) void attn_kernel(
    const u16* __restrict__ qkv, u16* __restrict__ OT) {
  int d = blockIdx.x;
  // Bijective on [0,512); 16 (b,h) groups x 256KB K/V = 4MB per XCD L2.
  int blk = ((((d & 7) << 4) | (d >> 5)) << 2) | ((d >> 3) & 3);
  int b = blk >> 5;
  int hh = (blk >> 2) & 7;   // head
  int q0 = (blk & 3) << 8;
  int t = threadIdx.x;
  int lane = t & 63, w = t >> 6;
  int l31 = lane & 31, hl = lane >> 5;

  __shared__ __align__(16) u16 Klds[2][64 * 72];  // [m][d]
  __shared__ __align__(16) u16 Vlds[2][64 * 72];  // [d][m]

  size_t hb = (size_t)b * OQKV + hh * 64;
  int qrow = q0 + (w << 5) + l31;

  // Q frags (B-operand of 32x32x16: col=lane&31=q, k = (lane>>5)*8+j),
  // pre-scaled by log2e/64 so exp(S) == exp2(S')
  const float QSC = 1.442695041f / 64.f;
  short8 qf[4];
#pragma unroll
  for (int ks = 0; ks < 4; ks++)
#pragma unroll
    for (int j = 0; j < 8; j++) {
      int dd = ks * 16 + (hl << 3) + j;
      qf[ks][j] = (short)f2us(us2f(qkv[(hb + dd) * NSP + qrow]) * QSC);
    }

  // ones A-fragment (bf16 1.0 in every slot) for the lsum column-sum MFMA
  short8 onesf;
#pragma unroll
  for (int j = 0; j < 8; j++) onesf[j] = (short)0x3F80;

  f32x16 oacc[2], lsacc;
#pragma unroll
  for (int dt = 0; dt < 2; dt++)
#pragma unroll
    for (int e = 0; e < 16; e++) oacc[dt][e] = 0.f;
#pragma unroll
  for (int e = 0; e < 16; e++) lsacc[e] = 0.f;

  bool isK = (t < 256);        // wave-uniform staging split
  int ts = t & 255;
  int m0k = (ts & 15) << 2;    // K-staging m
  int d0k = (ts >> 4) << 2;    // K-staging d
  int sdv = ts >> 2;           // V-staging d
  int sm0 = (ts & 3) << 4;     // V-staging m
  const u16* kbase = qkv + (hb + 512) * NSP;
  const u16* vbase = qkv + (hb + 1024 + sdv) * NSP;

  uint2 kr[4];
  uint4 vr0, vr1;
  auto preload = [&](int mc) {
    if (isK) {
#pragma unroll
      for (int i = 0; i < 4; i++)
        kr[i] = *(const uint2*)(kbase + (size_t)(d0k + i) * NSP + mc + m0k);
    } else {
      vr0 = *(const uint4*)(vbase + mc + sm0);
      vr1 = *(const uint4*)(vbase + mc + sm0 + 8);
    }
  };

  preload(0);
  int cur = 0;
  for (int mc = 0; mc < NSP; mc += 64) {
    // write buf[cur] (safe: all waves' reads of buf[cur] from chunk mc-128
    // were drained before barrier(mc-64), which we have passed)
    if (isK) {
      // K: 4x4 register transpose -> [m][d] b64 writes
#pragma unroll
      for (int j = 0; j < 4; j++) {
        u32 s0 = (j & 2) ? kr[0].y : kr[0].x;
        u32 s1 = (j & 2) ? kr[1].y : kr[1].x;
        u32 s2 = (j & 2) ? kr[2].y : kr[2].x;
        u32 s3 = (j & 2) ? kr[3].y : kr[3].x;
        int sh = (j & 1) << 4;
        uint2 wv;
        wv.x = ((s0 >> sh) & 0xffffu) | (((s1 >> sh) & 0xffffu) << 16);
        wv.y = ((s2 >> sh) & 0xffffu) | (((s3 >> sh) & 0xffffu) << 16);
        *(uint2*)&Klds[cur][(m0k + j) * 72 + d0k] = wv;
      }
    } else {
      *(uint4*)&Vlds[cur][sdv * 72 + sm0] = vr0;
      *(uint4*)&Vlds[cur][sdv * 72 + sm0 + 8] = vr1;
    }
    __syncthreads();  // buf[cur] ready for all waves
    if (mc + 64 < NSP) preload(mc + 64);  // overlap next loads with MFMA
#pragma unroll
    for (int mt = 0; mt < 2; mt++) {
      // ---- S^T = K.Q : D[m 32][q 32], k=d in 4 slices of 16 ----
      f32x16 s;
#pragma unroll
      for (int e = 0; e < 16; e++) s[e] = 0.f;
#pragma unroll
      for (int ks = 0; ks < 4; ks++) {
        short8 kf = *(const short8*)&Klds[cur][((mt << 5) + l31) * 72 + (ks << 4) + (hl << 3)];
        s = __builtin_amdgcn_mfma_f32_32x32x16_bf16(kf, qf[ks], s, 0, 0, 0);
      }
      // ---- exp2 + pack to bf16 pairs ----
      u32 pk[8];
#pragma unroll
      for (int i = 0; i < 8; i++) {
        float e0 = exp2f(s[2 * i]), e1 = exp2f(s[2 * i + 1]);
        pk[i] = pack2(e0, e1);
      }
      // ---- lane<->lane+32 exchange via v_permlane32_swap (no selects):
      // swap(a=o2,b=o0): b -> {hl0: own o0, hl1: partner o2} = wv.x
      //                  a -> {hl0: partner o0, hl1: own o2} = wv.z
      short8 pf[2];
#pragma unroll
      for (int ks2 = 0; ks2 < 2; ks2++) {
        u32 a0 = pk[4 * ks2 + 2], b0 = pk[4 * ks2 + 0];
        u32 a1 = pk[4 * ks2 + 3], b1 = pk[4 * ks2 + 1];
        asm volatile("v_permlane32_swap_b32 %0, %1" : "+v"(a0), "+v"(b0));
        asm volatile("v_permlane32_swap_b32 %0, %1" : "+v"(a1), "+v"(b1));
        uint4 wv;
        wv.x = b0;
        wv.y = b1;
        wv.z = a0;
        wv.w = a1;
        pf[ks2] = *reinterpret_cast<short8*>(&wv);
      }
      // ---- PV + column-sum: O += V.P^T ; lsacc += ones.P^T ----
#pragma unroll
      for (int ks2 = 0; ks2 < 2; ks2++) {
        lsacc = __builtin_amdgcn_mfma_f32_32x32x16_bf16(onesf, pf[ks2], lsacc, 0, 0, 0);
#pragma unroll
        for (int dt = 0; dt < 2; dt++) {
          short8 vf = *(const short8*)&Vlds[cur][((dt << 5) + l31) * 72 + (mt << 5) + (ks2 << 4) + (hl << 3)];
          oacc[dt] = __builtin_amdgcn_mfma_f32_32x32x16_bf16(vf, pf[ks2], oacc[dt], 0, 0, 0);
        }
      }
    }
    cur ^= 1;
  }
  // ---- normalize + transposed store: OT[b][q][hh*64+d] ----
  float invL = 1.0f / lsacc[0];
  u16* op = OT + ((size_t)b * NSP + qrow) * NC + (hh << 6);
#pragma unroll
  for (int dt = 0; dt < 2; dt++)
#pragma unroll
    for (int g = 0; g < 4; g++) {
      uint2 pw;
      pw.x = pack2(oacc[dt][4 * g + 0] * invL, oacc[dt][4 * g + 1] * invL);
      pw.y = pack2(oacc[dt][4 * g + 2] * invL, oacc[dt][4 * g + 3] * invL);
      *(uint2*)&op[(dt << 5) + (g << 3) + (hl << 2)] = pw;
    }
}

extern "C" void kernel_launch(void* const* d_in, const int* in_sizes, int n_in,
                              void* d_out, int out_size, void* d_ws, size_t ws_size,
                              hipStream_t stream) {
  const void* x      = d_in[0];
  const void* norm_w = d_in[1];
  const void* norm_b = d_in[2];
  const void* qkv_w  = d_in[3];
  const void* qkv_b  = d_in[4];
  const void* proj_w = d_in[5];
  const void* proj_b = d_in[6];

  char* ws = (char*)d_ws;
  float2* part  = (float2*)ws;                      // [256] partial (s1,s2)
  u16* qkv = (u16*)(ws + 4096);                     // 48 MB: [B,3C,N] bf16
  u16* xnt = (u16*)(ws + 4096 + 50331648);          // 16 MB: XnT / OT (aliased)
  u16* wq  = (u16*)(ws + 4096 + 50331648 + 16777216);  // 1.5 MB qkv_w bf16
  u16* wp  = wq + OQKV * NC;                        // 0.5 MB proj_w bf16

  gn_partial<<<256, 256, 0, stream>>>(x, part);
  prep_all<<<2560, 256, 0, stream>>>(x, part, norm_w, norm_b,
                                     qkv_w, proj_w, wq, wp, xnt);
  mfma_gemm<false, false><<<dim3(8, 12, NB), 256, 0, stream>>>(
      wq, xnt, x, qkv_b, nullptr, qkv, OQKV);
  attn_kernel<<<512, 512, 0, stream>>>(qkv, xnt /* reused as OT */);
  mfma_gemm<true, true><<<dim3(8, 4, NB), 256, 0, stream>>>(
      wp, xnt, x, proj_b, x, d_out, NC);
}

// Round 16
// 225.349 us; speedup vs baseline: 1.0654x; 1.0654x over previous
//
#include <hip/hip_runtime.h>

#define NB 16
#define NC 512
#define NSP 1024
#define OQKV 1536
#define EPSV 1e-5f

typedef unsigned short u16;
typedef unsigned int u32;
typedef __attribute__((ext_vector_type(8))) short short8;
typedef __attribute__((ext_vector_type(4))) float f32x4;
typedef __attribute__((ext_vector_type(16))) float f32x16;

__device__ __forceinline__ float us2f(u16 u) {
  return __uint_as_float(((u32)u) << 16);
}
__device__ __forceinline__ u16 f2us(float f) {  // RNE f32->bf16
  u32 x = __float_as_uint(f);
  return (u16)((x + 0x7fffu + ((x >> 16) & 1u)) >> 16);
}
#if __has_builtin(__builtin_amdgcn_cvt_pk_bf16_f32)
typedef __attribute__((ext_vector_type(2))) __bf16 bf16x2_t;
__device__ __forceinline__ u32 pack2(float a, float b) {
  bf16x2_t r = __builtin_amdgcn_cvt_pk_bf16_f32(a, b);
  return *reinterpret_cast<u32*>(&r);
}
#else
__device__ __forceinline__ u32 pack2(float a, float b) {
  return (u32)f2us(a) | ((u32)f2us(b) << 16);
}
#endif
// raw hardware exp2: bare v_exp_f32 (precise exp2f pulls in OCML fixup code
// — r15 measured +11us from that; do NOT use libm exp2f here)
__device__ __forceinline__ float fexp2(float x) {
#if __has_builtin(__builtin_amdgcn_exp2f)
  return __builtin_amdgcn_exp2f(x);
#else
  return __expf(x * 0.6931471805599453f);
#endif
}
__device__ __forceinline__ float ld1(const void* p, size_t i, bool f32) {
  return f32 ? ((const float*)p)[i] : us2f(((const u16*)p)[i]);
}
// wave-uniform input-dtype detection (fp32 low-halves are random mantissa)
__device__ __forceinline__ bool detect_f32(const void* x0) {
  const u32* xw = (const u32*)x0;
  u32 w = xw[threadIdx.x & 63];
  u32 e = ((w & 0xffffu) >> 7) & 0xffu;
  bool sane = (e >= 0x60u && e <= 0x9fu);
  return __popcll(__ballot(sane)) < 32;
}

// async global->LDS, 16B per lane; lds ptr must be wave-uniform
typedef const __attribute__((address_space(1))) unsigned int* gas_t;
typedef __attribute__((address_space(3))) unsigned int* las_t;
__device__ __forceinline__ void gload16(const void* g, void* l) {
  __builtin_amdgcn_global_load_lds((gas_t)g, (las_t)l, 16, 0, 0);
}

// ---- GroupNorm partial sums: one block per (b,g,half); 32768 elems ----
__global__ __launch_bounds__(256) void gn_partial(
    const void* __restrict__ x, float2* __restrict__ part) {
  bool f32 = detect_f32(x);
  int idx = blockIdx.x;
  size_t base = (size_t)idx * 32768;
  float s1 = 0.f, s2 = 0.f;
  for (int i = threadIdx.x; i < 4096; i += 256) {
    float f[8];
    if (f32) {
      float4 a = *((const float4*)x + (base >> 2) + i * 2);
      float4 b = *((const float4*)x + (base >> 2) + i * 2 + 1);
      f[0]=a.x; f[1]=a.y; f[2]=a.z; f[3]=a.w; f[4]=b.x; f[5]=b.y; f[6]=b.z; f[7]=b.w;
    } else {
      uint4 p = *((const uint4*)x + (base >> 3) + i);
      f[0]=us2f((u16)(p.x&0xffffu)); f[1]=us2f((u16)(p.x>>16));
      f[2]=us2f((u16)(p.y&0xffffu)); f[3]=us2f((u16)(p.y>>16));
      f[4]=us2f((u16)(p.z&0xffffu)); f[5]=us2f((u16)(p.z>>16));
      f[6]=us2f((u16)(p.w&0xffffu)); f[7]=us2f((u16)(p.w>>16));
    }
#pragma unroll
    for (int m = 0; m < 8; m++) { s1 += f[m]; s2 += f[m] * f[m]; }
  }
  __shared__ float r1[256], r2[256];
  r1[threadIdx.x] = s1; r2[threadIdx.x] = s2;
  __syncthreads();
  for (int s = 128; s > 0; s >>= 1) {
    if ((int)threadIdx.x < s) {
      r1[threadIdx.x] += r1[threadIdx.x + s];
      r2[threadIdx.x] += r2[threadIdx.x + s];
    }
    __syncthreads();
  }
  if (threadIdx.x == 0) part[idx] = make_float2(r1[0], r2[0]);
}

// ---- fused prep: weight converts + GN-apply/transpose (stats inline) ----
__global__ __launch_bounds__(256) void prep_all(
    const void* __restrict__ x, const float2* __restrict__ part,
    const void* __restrict__ gamma, const void* __restrict__ beta,
    const void* __restrict__ qkvw, const void* __restrict__ projw,
    u16* __restrict__ wq, u16* __restrict__ wp, u16* __restrict__ xnt) {
  bool f32 = detect_f32(x);
  int p = blockIdx.x;
  int t = threadIdx.x;
  if (p < 512) {  // ---- weight fp32->bf16 convert (or copy) ----
    const void* src = (p < 384) ? qkvw : projw;
    u16* dst = (p < 384) ? wq : wp;
    size_t e = ((size_t)(p < 384 ? p : p - 384) * 256 + t) * 8;
    uint4 v;
    if (f32) {
      float4 a = *(const float4*)((const float*)src + e);
      float4 b = *(const float4*)((const float*)src + e + 4);
      v.x = pack2(a.x, a.y); v.y = pack2(a.z, a.w);
      v.z = pack2(b.x, b.y); v.w = pack2(b.z, b.w);
    } else {
      v = *(const uint4*)((const u16*)src + e);
    }
    *(uint4*)(dst + e) = v;
    return;
  }
  int q = p - 512;
  int b = q >> 7;
  int c0 = ((q >> 4) & 7) << 6;
  int n0 = (q & 15) << 6;
  __shared__ __align__(16) u16 T[64 * 64];
  int cc = t >> 4;         // 0..15
  int nn = (t & 15) << 2;  // 0..60
  float2 pa = part[((b << 3) + (c0 >> 6)) * 2];
  float2 pb = part[((b << 3) + (c0 >> 6)) * 2 + 1];
  float mean = (pa.x + pb.x) * (1.f / 65536.f);
  float var = (pa.y + pb.y) * (1.f / 65536.f) - mean * mean;
  float inv = rsqrtf(var + EPSV);
#pragma unroll
  for (int rep = 0; rep < 4; rep++) {
    int cl = cc + (rep << 4);     // c-local 0..63
    int c = c0 + cl;
    float g = ld1(gamma, c, f32), be = ld1(beta, c, f32);
    float wsc = g * inv, bsc = be - mean * wsc;
    size_t xb = ((size_t)b * NC + c) * NSP + n0 + nn;
    float f[4];
    if (f32) {
      float4 v = *(const float4*)((const float*)x + xb);
      f[0]=v.x; f[1]=v.y; f[2]=v.z; f[3]=v.w;
    } else {
      uint2 v = *(const uint2*)((const u16*)x + xb);
      f[0]=us2f((u16)(v.x&0xffffu)); f[1]=us2f((u16)(v.x>>16));
      f[2]=us2f((u16)(v.y&0xffffu)); f[3]=us2f((u16)(v.y>>16));
    }
#pragma unroll
    for (int j = 0; j < 4; j++) {
      int n = nn + j;
      T[(n << 6) + (((cl & ~7) ^ ((n & 7) << 3)) | (cl & 7))] =
          f2us(fmaf(f[j], wsc, bsc));
    }
  }
  __syncthreads();
#pragma unroll
  for (int i = 0; i < 2; i++) {
    int slot = (i << 8) + t;
    int nl = slot >> 3;         // 0..63
    int cs = (slot & 7) << 3;   // 0..56
    uint4 v = *(const uint4*)&T[(nl << 6) + (cs ^ ((nl & 7) << 3))];
    *(uint4*)&xnt[((size_t)b * NSP + n0 + nl) * NC + c0 + cs] = v;
  }
}

// ---- MFMA GEMM: out[b,o,n] = W[o,:].XnT[b,n,:] + bias. BK=64: 8 K-chunks
// x 2 barriers. LDS 32KB. Staging slot s=i*256+t: row=i*32+(t>>3), src seg
// = (t&7)^((t>>3)&7); reads XOR the same way (rule 21). Batch-grouping XCD
// swizzle (T1): xcd p&7 owns batches {2*xcd, 2*xcd+1}.
template <bool OUTRAW, bool RES>
__global__ __launch_bounds__(256) void mfma_gemm(
    const u16* __restrict__ W, const u16* __restrict__ Xt,
    const void* __restrict__ xdet, const void* __restrict__ bias,
    const void* __restrict__ res, void* __restrict__ out, int O) {
  bool f32 = detect_f32(xdet);
  bool of = OUTRAW && f32;
  int gy = O >> 7;                     // grid y-dim (12 or 4)
  int bpb = gy << 3;                   // blocks per batch
  int p = blockIdx.x + (blockIdx.y << 3) + blockIdx.z * bpb;
  int k = p >> 3;
  int b = ((p & 7) << 1) + (k >= bpb ? 1 : 0);
  int r = k - (k >= bpb ? bpb : 0);
  int orow = (r >> 3) << 7;
  int ncol = (r & 7) << 7;
  int t = threadIdx.x;
  int lane = t & 63, w = t >> 6;
  int wo = (w >> 1) << 6, wn = (w & 1) << 6;
  int l15 = lane & 15, quad = lane >> 4;

  __shared__ __align__(16) u16 Alds[128 * 64];
  __shared__ __align__(16) u16 Blds[128 * 64];

  f32x4 acc[4][4];
#pragma unroll
  for (int i = 0; i < 4; i++)
#pragma unroll
    for (int j = 0; j < 4; j++) acc[i][j] = (f32x4){0.f, 0.f, 0.f, 0.f};

  int srow = t >> 3;                        // staging base row (call i adds i*32)
  int seg = (t & 7) ^ (srow & 7);           // source 16B-segment (call-invariant)
  const u16* wpA = W + (size_t)(orow + srow) * NC + (seg << 3);
  const u16* xpB = Xt + ((size_t)b * NSP + ncol + srow) * NC + (seg << 3);

  for (int k0 = 0; k0 < NC; k0 += 64) {
    __syncthreads();  // prior chunk's frag reads done
#pragma unroll
    for (int i = 0; i < 4; i++) {
      gload16(wpA + k0 + (size_t)i * (32 * NC), &Alds[(i << 11) + (w << 9)]);
      gload16(xpB + k0 + (size_t)i * (32 * NC), &Blds[(i << 11) + (w << 9)]);
    }
    __syncthreads();  // compiler drains vmcnt(0) before barrier
#pragma unroll
    for (int kk = 0; kk < 2; kk++) {
      short8 af[4], bf[4];
#pragma unroll
      for (int ot = 0; ot < 4; ot++) {
        int rr = wo + ot * 16 + l15;
        af[ot] = *(const short8*)&Alds[(rr << 6) + ((((kk << 2) + quad) ^ (rr & 7)) << 3)];
      }
#pragma unroll
      for (int nt = 0; nt < 4; nt++) {
        int rr = wn + nt * 16 + l15;
        bf[nt] = *(const short8*)&Blds[(rr << 6) + ((((kk << 2) + quad) ^ (rr & 7)) << 3)];
      }
#pragma unroll
      for (int ot = 0; ot < 4; ot++)
#pragma unroll
        for (int nt = 0; nt < 4; nt++)
          acc[ot][nt] = __builtin_amdgcn_mfma_f32_16x16x32_bf16(
              af[ot], bf[nt], acc[ot][nt], 0, 0, 0);
    }
  }
  // ---- epilogue ----
#pragma unroll
  for (int ot = 0; ot < 4; ot++) {
#pragma unroll
    for (int rr = 0; rr < 4; rr++) {
      int o = orow + wo + ot * 16 + (quad << 2) + rr;
      float bs = ld1(bias, o, f32);
      size_t rowb = ((size_t)b * O + o) * NSP + ncol + wn + l15;
#pragma unroll
      for (int nt = 0; nt < 4; nt++) {
        size_t idx = rowb + nt * 16;
        float v = acc[ot][nt][rr] + bs;
        if (RES) v += ld1(res, idx, f32);
        if (of) ((float*)out)[idx] = v;
        else ((u16*)out)[idx] = f2us(v);
      }
    }
  }
}

// ---- MFMA attention: 512-thread block = 256 q of one (b,h); 8 waves. ----
// r15 structure (32x32x16 MFMA, P in registers, permlane32 exchange, twin
// K/V buffers 1 barrier/chunk, XCD swizzle, Q pre-scaled by log2e/64,
// lsum via ones-MFMA). This round's single fix: exp2f (precise OCML,
// measured +11us of fixup VALU in r15) -> __builtin_amdgcn_exp2f (bare
// v_exp_f32). Reg: VGPR 64/128; spill sentinel = WRITE_SIZE ~16.4MB.
__global__ __launch_bounds__(512, 4) void attn_kernel(
    const u16* __restrict__ qkv, u16* __restrict__ OT) {
  int d = blockIdx.x;
  // Bijective on [0,512); 16 (b,h) groups x 256KB K/V = 4MB per XCD L2.
  int blk = ((((d & 7) << 4) | (d >> 5)) << 2) | ((d >> 3) & 3);
  int b = blk >> 5;
  int hh = (blk >> 2) & 7;   // head
  int q0 = (blk & 3) << 8;
  int t = threadIdx.x;
  int lane = t & 63, w = t >> 6;
  int l31 = lane & 31, hl = lane >> 5;

  __shared__ __align__(16) u16 Klds[2][64 * 72];  // [m][d]
  __shared__ __align__(16) u16 Vlds[2][64 * 72];  // [d][m]

  size_t hb = (size_t)b * OQKV + hh * 64;
  int qrow = q0 + (w << 5) + l31;

  // Q frags (B-operand of 32x32x16: col=lane&31=q, k = (lane>>5)*8+j),
  // pre-scaled by log2e/64 so exp(S) == exp2(S')
  const float QSC = 1.442695041f / 64.f;
  short8 qf[4];
#pragma unroll
  for (int ks = 0; ks < 4; ks++)
#pragma unroll
    for (int j = 0; j < 8; j++) {
      int dd = ks * 16 + (hl << 3) + j;
      qf[ks][j] = (short)f2us(us2f(qkv[(hb + dd) * NSP + qrow]) * QSC);
    }

  // ones A-fragment (bf16 1.0 in every slot) for the lsum column-sum MFMA
  short8 onesf;
#pragma unroll
  for (int j = 0; j < 8; j++) onesf[j] = (short)0x3F80;

  f32x16 oacc[2], lsacc;
#pragma unroll
  for (int dt = 0; dt < 2; dt++)
#pragma unroll
    for (int e = 0; e < 16; e++) oacc[dt][e] = 0.f;
#pragma unroll
  for (int e = 0; e < 16; e++) lsacc[e] = 0.f;

  bool isK = (t < 256);        // wave-uniform staging split
  int ts = t & 255;
  int m0k = (ts & 15) << 2;    // K-staging m
  int d0k = (ts >> 4) << 2;    // K-staging d
  int sdv = ts >> 2;           // V-staging d
  int sm0 = (ts & 3) << 4;     // V-staging m
  const u16* kbase = qkv + (hb + 512) * NSP;
  const u16* vbase = qkv + (hb + 1024 + sdv) * NSP;

  uint2 kr[4];
  uint4 vr0, vr1;
  auto preload = [&](int mc) {
    if (isK) {
#pragma unroll
      for (int i = 0; i < 4; i++)
        kr[i] = *(const uint2*)(kbase + (size_t)(d0k + i) * NSP + mc + m0k);
    } else {
      vr0 = *(const uint4*)(vbase + mc + sm0);
      vr1 = *(const uint4*)(vbase + mc + sm0 + 8);
    }
  };

  preload(0);
  int cur = 0;
  for (int mc = 0; mc < NSP; mc += 64) {
    // write buf[cur] (safe: all waves' reads of buf[cur] from chunk mc-128
    // were drained before barrier(mc-64), which we have passed)
    if (isK) {
      // K: 4x4 register transpose -> [m][d] b64 writes
#pragma unroll
      for (int j = 0; j < 4; j++) {
        u32 s0 = (j & 2) ? kr[0].y : kr[0].x;
        u32 s1 = (j & 2) ? kr[1].y : kr[1].x;
        u32 s2 = (j & 2) ? kr[2].y : kr[2].x;
        u32 s3 = (j & 2) ? kr[3].y : kr[3].x;
        int sh = (j & 1) << 4;
        uint2 wv;
        wv.x = ((s0 >> sh) & 0xffffu) | (((s1 >> sh) & 0xffffu) << 16);
        wv.y = ((s2 >> sh) & 0xffffu) | (((s3 >> sh) & 0xffffu) << 16);
        *(uint2*)&Klds[cur][(m0k + j) * 72 + d0k] = wv;
      }
    } else {
      *(uint4*)&Vlds[cur][sdv * 72 + sm0] = vr0;
      *(uint4*)&Vlds[cur][sdv * 72 + sm0 + 8] = vr1;
    }
    __syncthreads();  // buf[cur] ready for all waves
    if (mc + 64 < NSP) preload(mc + 64);  // overlap next loads with MFMA
#pragma unroll
    for (int mt = 0; mt < 2; mt++) {
      // ---- S^T = K.Q : D[m 32][q 32], k=d in 4 slices of 16 ----
      f32x16 s;
#pragma unroll
      for (int e = 0; e < 16; e++) s[e] = 0.f;
#pragma unroll
      for (int ks = 0; ks < 4; ks++) {
        short8 kf = *(const short8*)&Klds[cur][((mt << 5) + l31) * 72 + (ks << 4) + (hl << 3)];
        s = __builtin_amdgcn_mfma_f32_32x32x16_bf16(kf, qf[ks], s, 0, 0, 0);
      }
      // ---- exp2 (bare v_exp_f32) + pack to bf16 pairs ----
      u32 pk[8];
#pragma unroll
      for (int i = 0; i < 8; i++) {
        float e0 = fexp2(s[2 * i]), e1 = fexp2(s[2 * i + 1]);
        pk[i] = pack2(e0, e1);
      }
      // ---- lane<->lane+32 exchange via v_permlane32_swap (no selects):
      // swap(a=o2,b=o0): b -> {hl0: own o0, hl1: partner o2} = wv.x
      //                  a -> {hl0: partner o0, hl1: own o2} = wv.z
      short8 pf[2];
#pragma unroll
      for (int ks2 = 0; ks2 < 2; ks2++) {
        u32 a0 = pk[4 * ks2 + 2], b0 = pk[4 * ks2 + 0];
        u32 a1 = pk[4 * ks2 + 3], b1 = pk[4 * ks2 + 1];
        asm volatile("v_permlane32_swap_b32 %0, %1" : "+v"(a0), "+v"(b0));
        asm volatile("v_permlane32_swap_b32 %0, %1" : "+v"(a1), "+v"(b1));
        uint4 wv;
        wv.x = b0;
        wv.y = b1;
        wv.z = a0;
        wv.w = a1;
        pf[ks2] = *reinterpret_cast<short8*>(&wv);
      }
      // ---- PV + column-sum: O += V.P^T ; lsacc += ones.P^T ----
#pragma unroll
      for (int ks2 = 0; ks2 < 2; ks2++) {
        lsacc = __builtin_amdgcn_mfma_f32_32x32x16_bf16(onesf, pf[ks2], lsacc, 0, 0, 0);
#pragma unroll
        for (int dt = 0; dt < 2; dt++) {
          short8 vf = *(const short8*)&Vlds[cur][((dt << 5) + l31) * 72 + (mt << 5) + (ks2 << 4) + (hl << 3)];
          oacc[dt] = __builtin_amdgcn_mfma_f32_32x32x16_bf16(vf, pf[ks2], oacc[dt], 0, 0, 0);
        }
      }
    }
    cur ^= 1;
  }
  // ---- normalize + transposed store: OT[b][q][hh*64+d] ----
  float invL = 1.0f / lsacc[0];
  u16* op = OT + ((size_t)b * NSP + qrow) * NC + (hh << 6);
#pragma unroll
  for (int dt = 0; dt < 2; dt++)
#pragma unroll
    for (int g = 0; g < 4; g++) {
      uint2 pw;
      pw.x = pack2(oacc[dt][4 * g + 0] * invL, oacc[dt][4 * g + 1] * invL);
      pw.y = pack2(oacc[dt][4 * g + 2] * invL, oacc[dt][4 * g + 3] * invL);
      *(uint2*)&op[(dt << 5) + (g << 3) + (hl << 2)] = pw;
    }
}

extern "C" void kernel_launch(void* const* d_in, const int* in_sizes, int n_in,
                              void* d_out, int out_size, void* d_ws, size_t ws_size,
                              hipStream_t stream) {
  const void* x      = d_in[0];
  const void* norm_w = d_in[1];
  const void* norm_b = d_in[2];
  const void* qkv_w  = d_in[3];
  const void* qkv_b  = d_in[4];
  const void* proj_w = d_in[5];
  const void* proj_b = d_in[6];

  char* ws = (char*)d_ws;
  float2* part  = (float2*)ws;                      // [256] partial (s1,s2)
  u16* qkv = (u16*)(ws + 4096);                     // 48 MB: [B,3C,N] bf16
  u16* xnt = (u16*)(ws + 4096 + 50331648);          // 16 MB: XnT / OT (aliased)
  u16* wq  = (u16*)(ws + 4096 + 50331648 + 16777216);  // 1.5 MB qkv_w bf16
  u16* wp  = wq + OQKV * NC;                        // 0.5 MB proj_w bf16

  gn_partial<<<256, 256, 0, stream>>>(x, part);
  prep_all<<<2560, 256, 0, stream>>>(x, part, norm_w, norm_b,
                                     qkv_w, proj_w, wq, wp, xnt);
  mfma_gemm<false, false><<<dim3(8, 12, NB), 256, 0, stream>>>(
      wq, xnt, x, qkv_b, nullptr, qkv, OQKV);
  attn_kernel<<<512, 512, 0, stream>>>(qkv, xnt /* reused as OT */);
  mfma_gemm<true, true><<<dim3(8, 4, NB), 256, 0, stream>>>(
      wp, xnt, x, proj_b, x, d_out, NC);
}